// Round 1
// baseline (821.644 us; speedup 1.0000x reference)
//
#include <hip/hip_runtime.h>

// Decoder: est[bc][f][w] = dot(A[bc][f][:], B[w][:]), then overlap-add step 8:
// out[bc][8k + i] = est[k][i] + est[k-1][8+i],  k = 0..F (est[-1]=est[F]=0)
//
// A: [16][16000][512] fp32 (524 MB, HBM-streamed), B: [16][512] fp32 (32 KB),
// out: [16][128008] fp32.

#define FRAMES 16000
#define EDIM 512
#define WDIM 16
#define KC 32                    // K-chunk staged per barrier
#define NCHUNK (EDIM / KC)       // 16
#define ROWS 256                 // frames (threads) per block
#define LDS_STRIDE (KC + 4)      // 36 floats: 144 B rows, 16-B aligned, bank-balanced
#define OUT_PER_BC (8 * (FRAMES + 1))   // 128008

__global__ __launch_bounds__(256, 4)
void decoder_kernel(const float* __restrict__ A,
                    const float* __restrict__ B,
                    float* __restrict__ out)
{
    __shared__ float lds_a[ROWS * LDS_STRIDE];   // 36864 B -> 4 blocks/CU

    const int  t  = threadIdx.x;
    const int  bc = blockIdx.y;                  // 0..15 = b*2+c
    const long f0 = (long)blockIdx.x * 255 - 1;  // block covers frames f0..f0+255,
                                                 // writes sub-blocks f0+1..f0+255
    const long f  = f0 + t;                      // this thread's frame
    const bool valid = (f >= 0) && (f < FRAMES);

    const float* Abc = A + (size_t)bc * FRAMES * EDIM;

    // Staging assignment: thread t owns float4-slot (t&7) of rows i*32 + (t>>3).
    // Lanes 0..7 form one contiguous 128-B global segment per row.
    const int slot  = t & 7;
    const int rbase = t >> 3;

    size_t rowoff[8];
    #pragma unroll
    for (int i = 0; i < 8; ++i) {
        long fr = f0 + (long)(i * 32 + rbase);
        if (fr < 0) fr = 0;                       // clamp: safe addr for ghost rows
        if (fr >= FRAMES) fr = FRAMES - 1;        // (their acc is zeroed later)
        rowoff[i] = (size_t)fr * EDIM + (size_t)(slot * 4);
    }

    float acc[WDIM];
    #pragma unroll
    for (int w = 0; w < WDIM; ++w) acc[w] = 0.f;

    for (int c = 0; c < NCHUNK; ++c) {
        // ---- stage A chunk: 256 rows x 32 floats, padded stride 36 ----
        float4 v[8];
        #pragma unroll
        for (int i = 0; i < 8; ++i)
            v[i] = *(const float4*)(Abc + rowoff[i] + (size_t)(c * KC));
        #pragma unroll
        for (int i = 0; i < 8; ++i) {
            const int r = i * 32 + rbase;
            *(float4*)(&lds_a[r * LDS_STRIDE + slot * 4]) = v[i];
        }
        __syncthreads();

        // ---- compute: 32 k-steps x 16 w FMAs; B via uniform (scalar) loads ----
        #pragma unroll
        for (int j = 0; j < 8; ++j) {
            const float4 a = *(const float4*)(&lds_a[t * LDS_STRIDE + j * 4]);
            const float* Bk = B + c * KC + j * 4;   // wave-uniform address
            #pragma unroll
            for (int w = 0; w < WDIM; ++w) {
                float s = acc[w];
                s = fmaf(a.x, Bk[w * EDIM + 0], s);
                s = fmaf(a.y, Bk[w * EDIM + 1], s);
                s = fmaf(a.z, Bk[w * EDIM + 2], s);
                s = fmaf(a.w, Bk[w * EDIM + 3], s);
                acc[w] = s;
            }
        }
        __syncthreads();
    }

    // ghost frames (f=-1 or f>=F) must contribute zero
    if (!valid) {
        #pragma unroll
        for (int w = 0; w < WDIM; ++w) acc[w] = 0.f;
    }

    // ---- overlap-add: pass est[f][8..15] to thread t+1 via LDS (reuse lds_a) ----
    #pragma unroll
    for (int i = 0; i < 8; ++i) lds_a[t * 8 + i] = acc[8 + i];
    __syncthreads();

    // thread t writes output sub-block k = f (8 floats), needs est[k-1][8..15]
    if (t >= 1 && f >= 0 && f <= FRAMES) {
        float r0[8];
        #pragma unroll
        for (int i = 0; i < 8; ++i) r0[i] = acc[i] + lds_a[(t - 1) * 8 + i];
        float* o = out + (size_t)bc * OUT_PER_BC + (size_t)f * 8;
        *(float4*)(o)     = make_float4(r0[0], r0[1], r0[2], r0[3]);
        *(float4*)(o + 4) = make_float4(r0[4], r0[5], r0[6], r0[7]);
    }
}

extern "C" void kernel_launch(void* const* d_in, const int* in_sizes, int n_in,
                              void* d_out, int out_size, void* d_ws, size_t ws_size,
                              hipStream_t stream) {
    const float* A   = (const float*)d_in[0];   // mixture_w [8*2*16000*512]
    const float* B   = (const float*)d_in[1];   // basis_weight [16*512]
    float*       out = (float*)d_out;           // [8*2*128008]

    dim3 grid(63, 16, 1);   // 63 = ceil((FRAMES+1)/255) sub-block groups, 16 = b*c
    decoder_kernel<<<grid, dim3(256, 1, 1), 0, stream>>>(A, B, out);
}

// Round 2
// 749.137 us; speedup vs baseline: 1.0968x; 1.0968x over previous
//
#include <hip/hip_runtime.h>

// est[bc][f][w] = dot(A[bc][f][:], B[w][:]);  out[bc][8f+i] = est[f][i] + est[f-1][8+i]
// A: [16][16000][512] fp32 (524 MB HBM stream), B: [16][512] (held in VGPRs), out: [16][128008].
//
// One wave per 128 output frames. Lane split: wq = l&7 -> w in {2wq,2wq+1};
// ksl = l>>3 -> k in [ksl*64, ksl*64+64). B-regs: 2w x 64k = 128 VGPR/lane.
// A loads: lane-contiguous dwordx4, 8 distinct 128B lines per inst, full row
// consumed across the frame's 16 insts (no overfetch). Reduce over ksl: 3 shfl_xor.

#define FRAMES 16000
#define EDIM   512
#define OUTF   16001               // output sub-blocks per bc (frames 0..16000)
#define OUT_PER_BC 128008          // 8 * OUTF
#define BATCHES 16
#define OFPW    128                // output frames per wave

__global__ __launch_bounds__(128, 2)
void decoder_kernel(const float* __restrict__ A,
                    const float* __restrict__ B,
                    float* __restrict__ out)
{
    const int t   = threadIdx.x;
    const int wid = t >> 6;            // wave in block
    const int l   = t & 63;
    const int wq  = l & 7;             // w-pair index
    const int ksl = l >> 3;            // k-slice index
    const int bc  = blockIdx.y;
    const int o0  = (blockIdx.x * 2 + wid) * OFPW;

    __shared__ float ring[2][16][16];  // per-wave est ring: [wave][frame&15][w]

    // ---- B into registers: Bw[w'][h][j] = B[2wq+w'][ksl*64 + h*32 + 4j .. +3]
    const float4* B4 = (const float4*)B;
    float4 Bw[2][2][8];
    #pragma unroll
    for (int w = 0; w < 2; ++w)
        #pragma unroll
        for (int h = 0; h < 2; ++h)
            #pragma unroll
            for (int j = 0; j < 8; ++j)
                Bw[w][h][j] = B4[(2*wq + w) * 128 + ksl*16 + h*8 + j];

    const float4* Abc = (const float4*)(A + (size_t)bc * FRAMES * EDIM);
    // frame f, half h, j: float4 index f*128 + ksl*16 + h*8 + j

    float4 Abuf[2][8];                 // half-row ping-pong (1 KB/wave each)

    auto loadHalf = [&](float4* dst, int f, int h) {
        int fc = f; if (fc < 0) fc = 0; if (fc >= FRAMES) fc = FRAMES - 1;
        const float4* p = Abc + (size_t)fc * 128 + ksl*16 + h*8;
        #pragma unroll
        for (int j = 0; j < 8; ++j) dst[j] = p[j];
    };

    // Invariant at processFrame(f) entry: Abuf[0] holds (f, h0).
    // On exit: Abuf[0] holds (f+1, h0).
    auto processFrame = [&](int f) {
        loadHalf(Abuf[1], f, 1);                   // (f, h1) in flight
        float acc[2][2] = {{0.f,0.f},{0.f,0.f}};   // [w'][h] chains
        #pragma unroll
        for (int j = 0; j < 8; ++j) {              // compute h0
            const float4 a = Abuf[0][j];
            acc[0][0] = fmaf(a.x, Bw[0][0][j].x, acc[0][0]);
            acc[0][0] = fmaf(a.y, Bw[0][0][j].y, acc[0][0]);
            acc[0][0] = fmaf(a.z, Bw[0][0][j].z, acc[0][0]);
            acc[0][0] = fmaf(a.w, Bw[0][0][j].w, acc[0][0]);
            acc[1][0] = fmaf(a.x, Bw[1][0][j].x, acc[1][0]);
            acc[1][0] = fmaf(a.y, Bw[1][0][j].y, acc[1][0]);
            acc[1][0] = fmaf(a.z, Bw[1][0][j].z, acc[1][0]);
            acc[1][0] = fmaf(a.w, Bw[1][0][j].w, acc[1][0]);
        }
        loadHalf(Abuf[0], f + 1, 0);               // (f+1, h0) in flight
        #pragma unroll
        for (int j = 0; j < 8; ++j) {              // compute h1
            const float4 a = Abuf[1][j];
            acc[0][1] = fmaf(a.x, Bw[0][1][j].x, acc[0][1]);
            acc[0][1] = fmaf(a.y, Bw[0][1][j].y, acc[0][1]);
            acc[0][1] = fmaf(a.z, Bw[0][1][j].z, acc[0][1]);
            acc[0][1] = fmaf(a.w, Bw[0][1][j].w, acc[0][1]);
            acc[1][1] = fmaf(a.x, Bw[1][1][j].x, acc[1][1]);
            acc[1][1] = fmaf(a.y, Bw[1][1][j].y, acc[1][1]);
            acc[1][1] = fmaf(a.z, Bw[1][1][j].z, acc[1][1]);
            acc[1][1] = fmaf(a.w, Bw[1][1][j].w, acc[1][1]);
        }
        float r0 = acc[0][0] + acc[0][1];
        float r1 = acc[1][0] + acc[1][1];
        r0 += __shfl_xor(r0, 8);   r1 += __shfl_xor(r1, 8);    // reduce over ksl
        r0 += __shfl_xor(r0, 16);  r1 += __shfl_xor(r1, 16);
        r0 += __shfl_xor(r0, 32);  r1 += __shfl_xor(r1, 32);
        if (f < 0 || f >= FRAMES) { r0 = 0.f; r1 = 0.f; }      // ghost frames
        if (ksl == 0) {                                        // 8 lanes write est[f][:]
            *(float2*)&ring[wid][f & 15][2*wq] = make_float2(r0, r1);
        }
    };

    loadHalf(Abuf[0], o0 - 1, 0);
    processFrame(o0 - 1);                          // prologue: est[o0-1] into ring

    for (int b = 0; b < BATCHES; ++b) {
        const int cf = o0 + b * 8;
        #pragma unroll
        for (int r = 0; r < 8; ++r) processFrame(cf + r);
        __syncthreads();                           // ring write->read visibility
        // overlap-add epilogue: 64 contiguous outputs (frames cf..cf+7)
        const int fr = cf + (l >> 3);
        const float v = ring[wid][fr & 15][l & 7]
                      + ring[wid][(fr - 1) & 15][8 + (l & 7)];
        if (fr < OUTF)
            out[(size_t)bc * OUT_PER_BC + (size_t)cf * 8 + l] = v;
    }
}

extern "C" void kernel_launch(void* const* d_in, const int* in_sizes, int n_in,
                              void* d_out, int out_size, void* d_ws, size_t ws_size,
                              hipStream_t stream) {
    const float* A   = (const float*)d_in[0];   // mixture_w
    const float* B   = (const float*)d_in[1];   // basis_weight [16][512]
    float*       out = (float*)d_out;

    // 126 waves per bc (63 blocks x 2 waves), 128 output frames each -> covers 16001
    dim3 grid(63, 16, 1);
    decoder_kernel<<<grid, dim3(128, 1, 1), 0, stream>>>(A, B, out);
}